// Round 19
// baseline (445.258 us; speedup 1.0000x reference)
//
#include <hip/hip_runtime.h>
#include <cstddef>

#define U_CNT 20000
#define I_CNT 15000
#define N_CNT 35000
#define A_CNT 2048
#define NC_K  2048
#define EAU   300000
#define EUI   300000
#define ER    60000
#define NLIST 14

__device__ __forceinline__ float4 ld4(const float* p){ return *reinterpret_cast<const float4*>(p); }
__device__ __forceinline__ void st4(float* p, float4 v){ *reinterpret_cast<float4*>(p) = v; }
__device__ __forceinline__ float4 mul4(float4 a, float4 b){ return make_float4(a.x*b.x, a.y*b.y, a.z*b.z, a.w*b.w); }
__device__ __forceinline__ float4 add4(float4 a, float4 b){ return make_float4(a.x+b.x, a.y+b.y, a.z+b.z, a.w+b.w); }
__device__ __forceinline__ float4 fmas4(float s, float4 b, float4 c){
  return make_float4(fmaf(s,b.x,c.x), fmaf(s,b.y,c.y), fmaf(s,b.z,c.z), fmaf(s,b.w,c.w));
}
__device__ __forceinline__ unsigned short f2bf(float x){           // RNE f32->bf16
  unsigned u = __float_as_uint(x);
  u += 0x7fffu + ((u >> 16) & 1u);
  return (unsigned short)(u >> 16);
}
__device__ __forceinline__ float bf2f(unsigned short s){
  return __uint_as_float(((unsigned)s) << 16);
}

// fp32 GEMM core (r8 form — 2.45 TB/s effective at SPLIT=4, occ 85%):
// BM=64, BN=64, BK=32, 256 threads, 4x4 micro-tile, LDS-staged A and W.
// Session A/B: MFMA cores cap at ~1.7 TB/s (32KB/block-step L2 B-plane
// traffic contends with A-stream); this core reads W once into LDS.
__device__ __forceinline__ void gemm_core(
    const float* __restrict__ A, int lda, int M, int r0,
    const float* __restrict__ W, int k0base, int kcount,
    float* __restrict__ smem, float4* accs)
{
  float (*As)[36] = (float (*)[36])smem;
  float (*Ws)[64] = (float (*)[64])(smem + 64*36);
  const int t = threadIdx.x;
  const int ty = t >> 4, tx = t & 15;
  float4 acc0 = make_float4(0,0,0,0), acc1 = acc0, acc2 = acc0, acc3 = acc0;
  for (int k0 = k0base; k0 < k0base + kcount; k0 += 32) {
    __syncthreads();
    #pragma unroll
    for (int i = 0; i < 2; ++i) {
      int f = t + i*256;
      int row = f >> 3, caa = (f & 7) << 2;
      float4 v = make_float4(0.f,0.f,0.f,0.f);
      int r = r0 + row;
      if (r < M) v = ld4(&A[(size_t)r*lda + k0 + caa]);
      st4(&As[row][caa], v);
      int kk = f >> 4, cb = (f & 15) << 2;
      st4(&Ws[kk][cb], ld4(&W[(size_t)(k0+kk)*64 + cb]));
    }
    __syncthreads();
    #pragma unroll
    for (int kk = 0; kk < 32; kk += 4) {
      float4 a0 = ld4(&As[ty*4+0][kk]);
      float4 a1 = ld4(&As[ty*4+1][kk]);
      float4 a2 = ld4(&As[ty*4+2][kk]);
      float4 a3 = ld4(&As[ty*4+3][kk]);
      float a0v[4] = {a0.x,a0.y,a0.z,a0.w};
      float a1v[4] = {a1.x,a1.y,a1.z,a1.w};
      float a2v[4] = {a2.x,a2.y,a2.z,a2.w};
      float a3v[4] = {a3.x,a3.y,a3.z,a3.w};
      #pragma unroll
      for (int j = 0; j < 4; ++j) {
        float4 wv = ld4(&Ws[kk+j][tx<<2]);
        acc0 = fmas4(a0v[j], wv, acc0);
        acc1 = fmas4(a1v[j], wv, acc1);
        acc2 = fmas4(a2v[j], wv, acc2);
        acc3 = fmas4(a3v[j], wv, acc3);
      }
    }
  }
  accs[0]=acc0; accs[1]=acc1; accs[2]=acc2; accs[3]=acc3;
}

// tiny standalone: head[] = -1
__global__ __launch_bounds__(256) void fill_m1(int4* __restrict__ p, int n4)
{
  int gid = blockIdx.x*256 + threadIdx.x;
  if (gid < n4) p[gid] = make_int4(-1,-1,-1,-1);
}

// ========== MEGA1: splitk(fp32, bf16 parts) | build | k64 aspect | k64 review(bf16) | fe1c | sigtab ==========
struct Mega1Args {
  int e_sp, e_build, e_k64a, e_k64r, e_fe1c, split;
  const float* emb[6]; float* sigt;
  const float* f1; const float* cui; const float* ciu; float* fe1c;
  const float* spA[2]; const float* spW[2]; unsigned short* spPart[2]; int spM[2];
  const float* aA[2]; const float* aW[2]; const float* aMul[2]; float* aC[2];
  const float* rA[10]; const float* rW[10]; unsigned short* rC[10];
  const int* bsrc[NLIST]; const int* bdst[NLIST];
  const int* rat2; const int* rat3;
  int2* node[NLIST]; int* head[NLIST];
};

__global__ __launch_bounds__(256, 8) void mega1(Mega1Args a)
{
  __shared__ float smem[64*36 + 32*64];
  int b = blockIdx.x, t = threadIdx.x;
  const int ty = t >> 4, tx = t & 15;
  if (b < a.e_sp) {
    int nb0 = a.split*313;
    int side, sp, bx;
    if (b < nb0) { side = 0; sp = b/313; bx = b%313; }
    else         { int b2 = b-nb0; side = 1; sp = b2/235; bx = b2%235; }
    int M = a.spM[side];
    int r0 = bx*64;
    int kchunk = NC_K/a.split;
    float4 accs[4];
    gemm_core(a.spA[side], NC_K, M, r0, a.spW[side], sp*kchunk, kchunk, smem, accs);
    unsigned short* base = a.spPart[side] + (size_t)sp * M * 64;
    #pragma unroll
    for (int i = 0; i < 4; ++i) {
      int r = r0 + ty*4 + i;
      if (r < M) {
        ushort4 o4;
        o4.x = f2bf(accs[i].x); o4.y = f2bf(accs[i].y);
        o4.z = f2bf(accs[i].z); o4.w = f2bf(accs[i].w);
        *reinterpret_cast<ushort4*>(&base[(size_t)r*64 + (tx<<2)]) = o4;
      }
    }
    return;
  }
  if (b < a.e_build) {
    int local = b - a.e_sp;
    int li, bx;
    if (local < 4*1172) { li = local/1172; bx = local%1172; }
    else { int l2 = local - 4*1172; li = 4 + l2/235; bx = l2%235; }
    int E = (li < 4) ? EAU : ER;
    int i = bx*256 + t;
    if (i < E) {
      int d = a.bdst[li][i];
      int pay = a.bsrc[li][i];
      if (li == 2) pay |= a.rat2[i] << 20;
      else if (li == 3) pay |= a.rat3[i] << 20;
      int prev = atomicExch(&a.head[li][d], i);
      a.node[li][i] = make_int2(prev, pay);
    }
    return;
  }
  if (b < a.e_k64a) {                                  // aspect GEMMs: 2 x 32, f32 out
    int local = b - a.e_build;
    int z = local/32, bx = local%32;
    int r0 = bx*64;
    float4 accs[4];
    gemm_core(a.aA[z], 64, A_CNT, r0, a.aW[z], 0, 64, smem, accs);
    const float* mulp = a.aMul[z];
    float* C = a.aC[z];
    #pragma unroll
    for (int i = 0; i < 4; ++i) {
      int r = r0 + ty*4 + i;
      size_t o = (size_t)r*64 + (tx<<2);
      st4(&C[o], mul4(accs[i], ld4(&mulp[o])));
    }
    return;
  }
  if (b < a.e_k64r) {                                  // review GEMMs: 10 x 938, bf16 out
    int local = b - a.e_k64a;
    int z = local/938, bx = local%938;
    int r0 = bx*64;
    float4 accs[4];
    gemm_core(a.rA[z], 64, ER, r0, a.rW[z], 0, 64, smem, accs);
    unsigned short* C = a.rC[z];
    #pragma unroll
    for (int i = 0; i < 4; ++i) {
      int r = r0 + ty*4 + i;
      if (r < ER) {
        ushort4 o4;
        o4.x = f2bf(accs[i].x); o4.y = f2bf(accs[i].y);
        o4.z = f2bf(accs[i].z); o4.w = f2bf(accs[i].w);
        *reinterpret_cast<ushort4*>(&C[(size_t)r*64 + (tx<<2)]) = o4;
      }
    }
    return;
  }
  if (b < a.e_fe1c) {
    int gid = (b - a.e_k64r)*256 + t;
    if (gid < N_CNT*16) {
      int n = gid >> 4, q = (gid & 15) << 2;
      size_t o = (size_t)n*64 + q;
      float4 v = ld4(&a.f1[o]);
      float4 c = (n < U_CNT) ? ld4(&a.cui[o]) : ld4(&a.ciu[(size_t)(n-U_CNT)*64 + q]);
      st4(&a.fe1c[o], mul4(v, c));
    }
    return;
  }
  {
    int gid = (b - a.e_fe1c)*256 + t;
    if (gid < 6*320) {
      int k = gid/320, j = gid%320;
      a.sigt[gid] = 1.f/(1.f + __expf(-a.emb[k][j]));
    }
  }
}

// ========== MEGA2: fe5 gathers (bf16 re) | aspect gather_blend | reduce_blend (bf16 parts) ==========
#define FE5Z 10
struct Mega2Args {
  int split;
  const int* f_head[FE5Z]; const int2* f_node[FE5Z];
  const unsigned short* f_re[FE5Z]; const float* f_w[FE5Z]; const float* f_cui[FE5Z];
  const float* f_cmul[FE5Z]; float* f_outA[FE5Z]; float* f_outB[FE5Z]; int f_n[FE5Z];
  const int* gb_head[2]; const int2* gb_node[2];
  const float* gb_msg[2]; const float* gb_mask[2]; const float* gb_ca[2];
  const float* gb_fe[2]; const float* gb_cui[2]; float* gb_out[2]; int gb_n[2];
  const unsigned short* part[2]; int M[2];
  const float* bias[2]; const float* mask[2];
  const float* ca[2]; const float* fe[2]; const float* cui[2]; float* outb[2];
};

__global__ __launch_bounds__(256) void mega2(Mega2Args a)
{
  int b = blockIdx.x, t = threadIdx.x;
  int q = (t & 15) << 2;
  const int B_FE5 = 5*1250 + 5*938;                    // 10940
  if (b < B_FE5) {
    int z, bx;
    if (b < 6250) { z = 2*(b/1250) + 1; bx = b%1250; } // iu-lists (users)
    else { int l2 = b - 6250; z = 2*(l2/938); bx = l2%938; } // ui-lists (items)
    int d = bx*16 + (t >> 4);
    if (d >= a.f_n[z]) return;
    const int2* __restrict__ node = a.f_node[z];
    const unsigned short* __restrict__ re = a.f_re[z];
    const float* __restrict__ w = a.f_w[z];
    const float* __restrict__ cuiS = a.f_cui[z];
    float4 a0 = make_float4(0,0,0,0), a1 = a0;
    for (int cur = a.f_head[z][d]; cur >= 0; ) {
      int2 nd = node[cur];
      int e = cur;
      cur = nd.x;
      int s = nd.y;
      ushort4 r4 = *reinterpret_cast<const ushort4*>(&re[(size_t)e*64 + q]);
      float4 rv = make_float4(bf2f(r4.x), bf2f(r4.y), bf2f(r4.z), bf2f(r4.w));
      float4 cv = ld4(&cuiS[(size_t)s*64 + q]);
      float4 wv = ld4(&w[(size_t)s*64 + q]);
      a0 = add4(a0, mul4(add4(wv, rv), cv));
      a1 = add4(a1, mul4(rv, cv));
    }
    float4 c = ld4(&a.f_cmul[z][(size_t)d*64 + q]);
    size_t o = (size_t)d*320 + q;
    st4(&a.f_outA[z][o], mul4(a0, c));
    st4(&a.f_outB[z][o], mul4(a1, c));
    return;
  }
  int local = b - B_FE5;
  if (local < 2188) {                                   // gather_blend: u 1250 | i 938
    int side = (local >= 1250);
    int bx = side ? (local - 1250) : local;
    int d = bx*16 + (t >> 4);
    if (d >= a.gb_n[side]) return;
    const int2* __restrict__ node = a.gb_node[side];
    const float* __restrict__ msg = a.gb_msg[side];
    float4 acc = make_float4(0,0,0,0);
    for (int cur = a.gb_head[side][d]; cur >= 0; ) {
      int2 nd = node[cur];
      cur = nd.x;
      acc = add4(acc, ld4(&msg[(size_t)nd.y*64 + q]));
    }
    size_t o = (size_t)d*64 + q;
    float m = a.gb_mask[side][d], im = 1.f - m;
    float4 cav = ld4(&a.gb_ca[side][o]), fev = ld4(&a.gb_fe[side][o]), cv = ld4(&a.gb_cui[side][o]);
    st4(&a.gb_out[side][o], make_float4((m*(acc.x*cav.x) + im*fev.x)*cv.x,
                                        (m*(acc.y*cav.y) + im*fev.y)*cv.y,
                                        (m*(acc.z*cav.z) + im*fev.z)*cv.z,
                                        (m*(acc.w*cav.w) + im*fev.w)*cv.w));
    return;
  }
  local -= 2188;                                        // reduce_blend: u 1250 | i 938
  int side = (local >= 1250);
  int gid = (side ? (local - 1250) : local)*256 + t;
  int M = a.M[side];
  if (gid >= M*16) return;
  int n = gid >> 4;
  float4 acc = ld4(&a.bias[side][q]);
  const unsigned short* part = a.part[side];
  for (int s = 0; s < a.split; ++s) {
    ushort4 p4 = *reinterpret_cast<const ushort4*>(&part[((size_t)s*M + n)*64 + q]);
    acc = add4(acc, make_float4(bf2f(p4.x), bf2f(p4.y), bf2f(p4.z), bf2f(p4.w)));
  }
  size_t o = (size_t)n*64 + q;
  float m = a.mask[side][n], im = 1.f - m;
  float4 cav = ld4(&a.ca[side][o]), fev = ld4(&a.fe[side][o]), cv = ld4(&a.cui[side][o]);
  st4(&a.outb[side][o], make_float4((m*(acc.x*cav.x) + im*fev.x)*cv.x,
                                    (m*(acc.y*cav.y) + im*fev.y)*cv.y,
                                    (m*(acc.z*cav.z) + im*fev.z)*cv.z,
                                    (m*(acc.w*cav.w) + im*fev.w)*cv.w));
}

// ========== MEGA3: fused 3-acc gathers -> outputs 1..3 ==========
struct Mega3Args {
  int e_g3i;
  const int* head[2]; const int2* node[2];
  const float* msgA[2]; const float* msgB[2]; const float* msgC[2];
  const float* sigA[2]; const float* sigB[2]; const float* sigC[2];
  const float* cmul[2]; float* outA[2]; float* outB[2]; float* outC[2]; int n[2];
};

__global__ __launch_bounds__(256) void mega3(Mega3Args a)
{
  int b = blockIdx.x, t = threadIdx.x;
  int side = (b >= a.e_g3i);
  int bx = side ? (b - a.e_g3i) : b;
  int d = bx*16 + (t >> 4);
  if (d >= a.n[side]) return;
  int q = (t & 15) << 2;
  const int2* __restrict__ node = a.node[side];
  const float* __restrict__ msgA = a.msgA[side];
  const float* __restrict__ msgB = a.msgB[side];
  const float* __restrict__ msgC = a.msgC[side];
  const float* __restrict__ sigA = a.sigA[side];
  const float* __restrict__ sigB = a.sigB[side];
  const float* __restrict__ sigC = a.sigC[side];
  float4 a0 = make_float4(0,0,0,0), a1 = a0, a2 = a0;
  for (int cur = a.head[side][d]; cur >= 0; ) {
    int2 nd = node[cur];
    cur = nd.x;
    int s = nd.y & 0xFFFFF;
    int r = nd.y >> 20;
    size_t so = (size_t)s*64 + q;
    int ro = r*64 + q;
    a0 = add4(a0, mul4(ld4(&msgA[so]), ld4(&sigA[ro])));
    a1 = add4(a1, mul4(ld4(&msgB[so]), ld4(&sigB[ro])));
    a2 = add4(a2, mul4(ld4(&msgC[so]), ld4(&sigC[ro])));
  }
  size_t o = (size_t)d*64 + q;
  float4 c = ld4(&a.cmul[side][o]);
  st4(&a.outA[side][o], mul4(a0, c));
  st4(&a.outB[side][o], mul4(a1, c));
  st4(&a.outC[side][o], mul4(a2, c));
}

extern "C" void kernel_launch(void* const* d_in, const int* in_sizes, int n_in,
                              void* d_out, int out_size, void* d_ws, size_t ws_size,
                              hipStream_t stream)
{
  (void)in_sizes; (void)n_in; (void)out_size;
  auto F = [&](int i){ return (const float*)d_in[i]; };
  auto Ix = [&](int i){ return (const int*)d_in[i]; };

  const float* feature1 = F(0);
  const float* feature2 = F(1);
  const float* feature3 = F(2);
  const float* weightK[5]   = {F(3),F(4),F(5),F(6),F(7)};
  const float* W_review1 = F(8);
  const float* W_review2 = F(9);
  const float* rating_emb[6] = {F(10),F(11),F(12),F(13),F(14),F(15)};
  const float* W_aspect  = F(16);
  const float* W_aspect2 = F(17);
  const float* W_count_user = F(18);
  const float* b_count_user = F(19);
  const float* W_count_item = F(20);
  const float* b_count_item = F(21);
  const float* aspect_fe  = F(22);
  const float* aspect_cau = F(23);
  const float* aspect_cai = F(24);
  const float* user_cau = F(25);
  const float* user_cui = F(26);
  const float* item_cai = F(27);
  const float* item_ciu = F(28);
  const float* user_cuiK[5] = {F(29),F(31),F(33),F(35),F(37)};
  const float* item_ciuK[5] = {F(30),F(32),F(34),F(36),F(38)};
  const float* user_mask = F(39);
  const float* item_mask = F(40);
  const float* user_aspect_count = F(41);
  const float* item_aspect_count = F(42);
  const float* uiK_review[5] = {F(45),F(47),F(49),F(51),F(53)};
  const float* iuK_review[5] = {F(46),F(48),F(50),F(52),F(54)};
  const int* au_src = Ix(55); const int* au_dst = Ix(56);
  const int* ai_src = Ix(57); const int* ai_dst = Ix(58);
  const int* ui_src = Ix(59); const int* ui_dst = Ix(60); const int* ui_rating = Ix(61);
  const int* iu_src = Ix(62); const int* iu_dst = Ix(63); const int* iu_rating = Ix(64);
  const int* uiK_src[5] = {Ix(65),Ix(69),Ix(73),Ix(77),Ix(81)};
  const int* uiK_dst[5] = {Ix(66),Ix(70),Ix(74),Ix(78),Ix(82)};
  const int* iuK_src[5] = {Ix(67),Ix(71),Ix(75),Ix(79),Ix(83)};
  const int* iuK_dst[5] = {Ix(68),Ix(72),Ix(76),Ix(80),Ix(84)};

  float* out  = (float*)d_out;
  float* out2 = out + (size_t)N_CNT*64;
  float* out3 = out + 2*(size_t)N_CNT*64;
  float* out4 = out + 3*(size_t)N_CNT*64;              // (N,320)
  float* out5 = out + 8*(size_t)N_CNT*64;              // (N,320)

  // ---- workspace ----
  float* ws = (float*)d_ws;
  size_t off = 0;
  auto alloc = [&](size_t n){ float* p = ws + off; off += (n + 3) & ~(size_t)3; return p; };
  float* sigt   = alloc(6*320);
  float* msg_au = alloc((size_t)A_CNT*64);
  float* msg_ai = alloc((size_t)A_CNT*64);
  float* h_u_a  = alloc((size_t)U_CNT*64);
  float* h_i_a  = alloc((size_t)I_CNT*64);
  float* g_u    = alloc((size_t)U_CNT*64);
  float* g_i    = alloc((size_t)I_CNT*64);
  float* fe1c   = alloc((size_t)N_CNT*64);

  // reb: 10 x ER x 64 bf16 (ushort)
  const size_t reUSH = (size_t)ER*64;
  float* rebf = alloc(10*reUSH/2);
  unsigned short* rebb[10];
  for (int j = 0; j < 10; ++j) rebb[j] = (unsigned short*)rebf + (size_t)j*reUSH;

  const int* l_src[NLIST] = {au_src, ai_src, ui_src, iu_src,
                             uiK_src[0],uiK_src[1],uiK_src[2],uiK_src[3],uiK_src[4],
                             iuK_src[0],iuK_src[1],iuK_src[2],iuK_src[3],iuK_src[4]};
  const int* l_dst[NLIST] = {au_dst, ai_dst, ui_dst, iu_dst,
                             uiK_dst[0],uiK_dst[1],uiK_dst[2],uiK_dst[3],uiK_dst[4],
                             iuK_dst[0],iuK_dst[1],iuK_dst[2],iuK_dst[3],iuK_dst[4]};
  int l_E[NLIST]    = {EAU,EAU,EUI,EUI, ER,ER,ER,ER,ER, ER,ER,ER,ER,ER};
  int l_nseg[NLIST] = {U_CNT,I_CNT,I_CNT,U_CNT, I_CNT,I_CNT,I_CNT,I_CNT,I_CNT,
                       U_CNT,U_CNT,U_CNT,U_CNT,U_CNT};

  int* ibase = (int*)(ws + off);
  int* lhead[NLIST]; int2* lnode[NLIST];
  size_t io = 0;
  for (int l = 0; l < NLIST; ++l) { lhead[l] = ibase + io; io += l_nseg[l]; }
  size_t head_ints = io;                                 // 245000
  for (int l = 0; l < NLIST; ++l) { lnode[l] = (int2*)(ibase + io); io += 2*(size_t)l_E[l]; }
  off += (io + 3) & ~(size_t)3;

  // parts: bf16 (ushort), SPLIT*N_CNT*64 ushorts
  int SPLIT = 4;
  while (SPLIT > 1 && (off + ((size_t)SPLIT*N_CNT*64 + 1)/2) * 4 > ws_size) SPLIT >>= 1;
  unsigned short* part_u = (unsigned short*)(ws + off);
  unsigned short* part_i = part_u + (size_t)SPLIT*U_CNT*64;

  // ---- fill heads ----
  fill_m1<<<(int)((head_ints/4 + 255)/256), 256, 0, stream>>>((int4*)ibase, (int)(head_ints/4));

  // ---- MEGA1 ----
  Mega1Args a1;
  const int B_SP    = SPLIT*313 + SPLIT*235;
  const int B_BUILD = 4*1172 + 10*235;                  // 7038
  const int B_K64A  = 64;
  const int B_K64R  = 10*938;                           // 9380
  const int B_FE1C  = (N_CNT*16 + 255)/256;             // 2188
  const int B_SIG   = 8;
  a1.e_sp    = B_SP;
  a1.e_build = B_SP + B_BUILD;
  a1.e_k64a  = a1.e_build + B_K64A;
  a1.e_k64r  = a1.e_k64a + B_K64R;
  a1.e_fe1c  = a1.e_k64r + B_FE1C;
  a1.split   = SPLIT;
  for (int k = 0; k < 6; ++k) a1.emb[k] = rating_emb[k];
  a1.sigt = sigt;
  a1.f1 = feature1; a1.cui = user_cui; a1.ciu = item_ciu; a1.fe1c = fe1c;
  a1.spA[0] = user_aspect_count; a1.spW[0] = W_count_user; a1.spPart[0] = part_u; a1.spM[0] = U_CNT;
  a1.spA[1] = item_aspect_count; a1.spW[1] = W_count_item; a1.spPart[1] = part_i; a1.spM[1] = I_CNT;
  a1.aA[0]=aspect_fe; a1.aW[0]=W_aspect;  a1.aMul[0]=aspect_cau; a1.aC[0]=msg_au;
  a1.aA[1]=aspect_fe; a1.aW[1]=W_aspect2; a1.aMul[1]=aspect_cai; a1.aC[1]=msg_ai;
  for (int k = 0; k < 5; ++k) {
    a1.rA[k]   = uiK_review[k]; a1.rW[k]   = W_review1; a1.rC[k]   = rebb[k];
    a1.rA[5+k] = iuK_review[k]; a1.rW[5+k] = W_review2; a1.rC[5+k] = rebb[5+k];
  }
  for (int l = 0; l < NLIST; ++l) {
    a1.bsrc[l]=l_src[l]; a1.bdst[l]=l_dst[l];
    a1.node[l]=lnode[l]; a1.head[l]=lhead[l];
  }
  a1.rat2 = ui_rating; a1.rat3 = iu_rating;
  mega1<<<a1.e_fe1c + B_SIG, 256, 0, stream>>>(a1);

  // ---- MEGA2 ----
  Mega2Args a2;
  a2.split = SPLIT;
  for (int k = 0; k < 5; ++k) {
    int z = 2*k;                                        // ui-side (dst=items)
    a2.f_head[z]=lhead[4+k]; a2.f_node[z]=lnode[4+k];
    a2.f_re[z]=rebb[k]; a2.f_w[z]=weightK[k]; a2.f_cui[z]=user_cuiK[k]; a2.f_cmul[z]=item_ciuK[k];
    a2.f_outA[z]=out4 + (size_t)U_CNT*320 + (size_t)k*64;
    a2.f_outB[z]=out5 + (size_t)U_CNT*320 + (size_t)k*64;
    a2.f_n[z]=I_CNT;
    a2.f_head[z+1]=lhead[9+k]; a2.f_node[z+1]=lnode[9+k]; // iu-side (dst=users)
    a2.f_re[z+1]=rebb[5+k]; a2.f_w[z+1]=weightK[k] + (size_t)U_CNT*64;
    a2.f_cui[z+1]=item_ciuK[k]; a2.f_cmul[z+1]=user_cuiK[k];
    a2.f_outA[z+1]=out4 + (size_t)k*64;
    a2.f_outB[z+1]=out5 + (size_t)k*64;
    a2.f_n[z+1]=U_CNT;
  }
  a2.gb_head[0]=lhead[0]; a2.gb_node[0]=lnode[0]; a2.gb_msg[0]=msg_au;
  a2.gb_mask[0]=user_mask; a2.gb_ca[0]=user_cau; a2.gb_fe[0]=feature2;
  a2.gb_cui[0]=user_cui; a2.gb_out[0]=h_u_a; a2.gb_n[0]=U_CNT;
  a2.gb_head[1]=lhead[1]; a2.gb_node[1]=lnode[1]; a2.gb_msg[1]=msg_ai;
  a2.gb_mask[1]=item_mask; a2.gb_ca[1]=item_cai; a2.gb_fe[1]=feature2 + (size_t)U_CNT*64;
  a2.gb_cui[1]=item_ciu; a2.gb_out[1]=h_i_a; a2.gb_n[1]=I_CNT;
  a2.part[0]=part_u; a2.M[0]=U_CNT; a2.bias[0]=b_count_user; a2.mask[0]=user_mask;
  a2.ca[0]=user_cau; a2.fe[0]=feature3; a2.cui[0]=user_cui; a2.outb[0]=g_u;
  a2.part[1]=part_i; a2.M[1]=I_CNT; a2.bias[1]=b_count_item; a2.mask[1]=item_mask;
  a2.ca[1]=item_cai; a2.fe[1]=feature3 + (size_t)U_CNT*64; a2.cui[1]=item_ciu; a2.outb[1]=g_i;
  const int B_M2 = (5*1250 + 5*938) + 2188 + 2188;
  mega2<<<B_M2, 256, 0, stream>>>(a2);

  // ---- MEGA3 ----
  Mega3Args a3;
  a3.e_g3i = 938;
  a3.head[0]=lhead[2]; a3.node[0]=lnode[2];
  a3.msgA[0]=h_u_a; a3.msgB[0]=g_u; a3.msgC[0]=fe1c;
  a3.sigA[0]=sigt + 0*320; a3.sigB[0]=sigt + 2*320; a3.sigC[0]=sigt + 4*320;
  a3.cmul[0]=item_ciu;
  a3.outA[0]=out + (size_t)U_CNT*64; a3.outB[0]=out2 + (size_t)U_CNT*64; a3.outC[0]=out3 + (size_t)U_CNT*64;
  a3.n[0]=I_CNT;
  a3.head[1]=lhead[3]; a3.node[1]=lnode[3];
  a3.msgA[1]=h_i_a; a3.msgB[1]=g_i; a3.msgC[1]=fe1c + (size_t)U_CNT*64;
  a3.sigA[1]=sigt + 1*320; a3.sigB[1]=sigt + 3*320; a3.sigC[1]=sigt + 5*320;
  a3.cmul[1]=user_cui;
  a3.outA[1]=out; a3.outB[1]=out2; a3.outC[1]=out3;
  a3.n[1]=U_CNT;
  mega3<<<938 + 1250, 256, 0, stream>>>(a3);
}

// Round 20
// 416.940 us; speedup vs baseline: 1.0679x; 1.0679x over previous
//
#include <hip/hip_runtime.h>
#include <cstddef>

#define U_CNT 20000
#define I_CNT 15000
#define N_CNT 35000
#define A_CNT 2048
#define NC_K  2048
#define EAU   300000
#define EUI   300000
#define ER    60000
#define NLIST 14

typedef __attribute__((ext_vector_type(8))) short bf16x8;
typedef __attribute__((ext_vector_type(4))) float f32x4;

__device__ __forceinline__ float4 ld4(const float* p){ return *reinterpret_cast<const float4*>(p); }
__device__ __forceinline__ void st4(float* p, float4 v){ *reinterpret_cast<float4*>(p) = v; }
__device__ __forceinline__ float4 mul4(float4 a, float4 b){ return make_float4(a.x*b.x, a.y*b.y, a.z*b.z, a.w*b.w); }
__device__ __forceinline__ float4 add4(float4 a, float4 b){ return make_float4(a.x+b.x, a.y+b.y, a.z+b.z, a.w+b.w); }
__device__ __forceinline__ unsigned short f2bf(float x){           // RNE f32->bf16
  unsigned u = __float_as_uint(x);
  u += 0x7fffu + ((u >> 16) & 1u);
  return (unsigned short)(u >> 16);
}
__device__ __forceinline__ float bf2f(unsigned short s){
  return __uint_as_float(((unsigned)s) << 16);
}

// split 8 f32 into bf16 hi/lo fragments (truncation split; residual ~2^-16)
__device__ __forceinline__ void cvt_hilo(float4 a, float4 b, bf16x8& h, bf16x8& l)
{
  float vv[8] = {a.x,a.y,a.z,a.w,b.x,b.y,b.z,b.w};
  #pragma unroll
  for (int j = 0; j < 8; ++j) {
    unsigned int bi = __float_as_uint(vv[j]);
    h[j] = (short)(bi >> 16);
    float hf = __uint_as_float(bi & 0xffff0000u);
    l[j] = (short)(__float_as_uint(vv[j] - hf) >> 16);
  }
}

// ===== MFMA GEMM core (r16/r18 form — session best). =====
// 64 rows x 64 cols per block, 4 waves (16 rows each). No LDS.
// W pre-converted fragment-ordered: Wp[(k>>3)*64 + c][j] = W[k][c].
// 3-term bf16x2: D += ah*bh + ah*bl + al*bh.
// Session A/B (r19): fp32-LDS core has higher raw BW but moves +45% more
// HBM bytes (write-allocate + lost L3 absorption) — net slower. Keep this.
__device__ __forceinline__ void gemm_mfma(
    const float* __restrict__ A, int lda, int M, int r0,
    const unsigned short* __restrict__ Wh, const unsigned short* __restrict__ Wl,
    int s0, int nsteps, f32x4* acc)
{
  const int t = threadIdx.x;
  const int w = t >> 6, l = t & 63;
  const int lr = l & 15, g = l >> 4;
  const int row = r0 + w*16 + lr;
  const bool rowok = row < M;
  const float* arow = A + (size_t)row*lda;
  for (int s = s0; s < s0 + nsteps; ++s) {
    float4 a0 = make_float4(0.f,0.f,0.f,0.f), a1 = a0;
    if (rowok) {
      a0 = ld4(arow + s*32 + g*8);
      a1 = ld4(arow + s*32 + g*8 + 4);
    }
    bf16x8 ah, al;
    cvt_hilo(a0, a1, ah, al);
    const unsigned short* bh_base = Wh + (size_t)(s*4 + g)*512;
    const unsigned short* bl_base = Wl + (size_t)(s*4 + g)*512;
    #pragma unroll
    for (int cb = 0; cb < 4; ++cb) {
      bf16x8 bh = *reinterpret_cast<const bf16x8*>(bh_base + (cb*16 + lr)*8);
      bf16x8 bl = *reinterpret_cast<const bf16x8*>(bl_base + (cb*16 + lr)*8);
      acc[cb] = __builtin_amdgcn_mfma_f32_16x16x32_bf16(ah, bh, acc[cb], 0, 0, 0);
      acc[cb] = __builtin_amdgcn_mfma_f32_16x16x32_bf16(ah, bl, acc[cb], 0, 0, 0);
      acc[cb] = __builtin_amdgcn_mfma_f32_16x16x32_bf16(al, bh, acc[cb], 0, 0, 0);
    }
  }
}

// ===== PREP: head fill + W fragment-order bf16 hi/lo pre-conversion =====
struct PrepArgs {
  int e_fill;
  int4* fillp; int fill_n4;
  const float* wsrc[6]; unsigned short* whi[6]; unsigned short* wlo[6];
  int welems[6]; int wblocks[6];
};

__global__ __launch_bounds__(256) void prep(PrepArgs a)
{
  int b = blockIdx.x, t = threadIdx.x;
  if (b < a.e_fill) {
    int gid = b*256 + t;
    if (gid < a.fill_n4) a.fillp[gid] = make_int4(-1,-1,-1,-1);
    return;
  }
  int local = b - a.e_fill;
  int z = 0;
  while (z < 5 && local >= a.wblocks[z]) { local -= a.wblocks[z]; ++z; }
  int e = local*256 + t;
  if (e >= a.welems[z]) return;
  int k = e >> 6, c = e & 63;
  int idx = ((k >> 3)*64 + c)*8 + (k & 7);
  float v = a.wsrc[z][e];
  unsigned int bi = __float_as_uint(v);
  a.whi[z][idx] = (unsigned short)(bi >> 16);
  float hf = __uint_as_float(bi & 0xffff0000u);
  a.wlo[z][idx] = (unsigned short)(__float_as_uint(v - hf) >> 16);
}

// ========== MEGA1: splitk(MFMA, bf16 parts) | build | k64 aspect | k64 review(bf16) | fe1c | sigtab ==========
struct Mega1Args {
  int e_sp, e_build, e_k64a, e_k64r, e_fe1c, split;
  const float* emb[6]; float* sigt;
  const float* f1; const float* cui; const float* ciu; float* fe1c;
  const float* spA[2]; const unsigned short* spWh[2]; const unsigned short* spWl[2];
  unsigned short* spPart[2]; int spM[2];
  const float* aA[2]; const unsigned short* aWh[2]; const unsigned short* aWl[2];
  const float* aMul[2]; float* aC[2];
  const float* rA[10]; const unsigned short* rWh[10]; const unsigned short* rWl[10];
  unsigned short* rC[10];
  const int* bsrc[NLIST]; const int* bdst[NLIST];
  const int* rat2; const int* rat3;
  int2* node[NLIST]; int* head[NLIST];
};

__global__ __launch_bounds__(256, 4) void mega1(Mega1Args a)
{
  int b = blockIdx.x, t = threadIdx.x;
  if (b < a.e_sp) {
    int nb0 = a.split*313;
    int side, sp, bx;
    if (b < nb0) { side = 0; sp = b/313; bx = b%313; }
    else         { int b2 = b-nb0; side = 1; sp = b2/235; bx = b2%235; }
    int M = a.spM[side];
    int r0 = bx*64;
    int spsteps = NC_K/(a.split*32);
    f32x4 acc[4];
    #pragma unroll
    for (int cb = 0; cb < 4; ++cb) acc[cb] = (f32x4){0.f,0.f,0.f,0.f};
    gemm_mfma(a.spA[side], NC_K, M, r0, a.spWh[side], a.spWl[side], sp*spsteps, spsteps, acc);
    unsigned short* base = a.spPart[side] + (size_t)sp * M * 64;
    int l = t & 63, w = t >> 6;
    int lr = l & 15, g = l >> 4;
    #pragma unroll
    for (int cb = 0; cb < 4; ++cb)
      #pragma unroll
      for (int i = 0; i < 4; ++i) {
        int r = r0 + w*16 + g*4 + i;
        if (r < M) base[(size_t)r*64 + cb*16 + lr] = f2bf(acc[cb][i]);
      }
    return;
  }
  if (b < a.e_build) {
    int local = b - a.e_sp;
    int li, bx;
    if (local < 4*1172) { li = local/1172; bx = local%1172; }
    else { int l2 = local - 4*1172; li = 4 + l2/235; bx = l2%235; }
    int E = (li < 4) ? EAU : ER;
    int i = bx*256 + t;
    if (i < E) {
      int d = a.bdst[li][i];
      int pay = a.bsrc[li][i];
      if (li == 2) pay |= a.rat2[i] << 20;
      else if (li == 3) pay |= a.rat3[i] << 20;
      int prev = atomicExch(&a.head[li][d], i);
      a.node[li][i] = make_int2(prev, pay);
    }
    return;
  }
  if (b < a.e_k64a) {                                  // aspect GEMMs: 2 x 32, f32 out
    int local = b - a.e_build;
    int z = local/32, bx = local%32;
    int r0 = bx*64;
    f32x4 acc[4];
    #pragma unroll
    for (int cb = 0; cb < 4; ++cb) acc[cb] = (f32x4){0.f,0.f,0.f,0.f};
    gemm_mfma(a.aA[z], 64, A_CNT, r0, a.aWh[z], a.aWl[z], 0, 2, acc);
    const float* mulp = a.aMul[z];
    float* C = a.aC[z];
    int l = t & 63, w = t >> 6;
    int lr = l & 15, g = l >> 4;
    #pragma unroll
    for (int cb = 0; cb < 4; ++cb)
      #pragma unroll
      for (int i = 0; i < 4; ++i) {
        int r = r0 + w*16 + g*4 + i;
        size_t o = (size_t)r*64 + cb*16 + lr;
        C[o] = acc[cb][i] * mulp[o];
      }
    return;
  }
  if (b < a.e_k64r) {                                  // review GEMMs: 10 x 938, bf16 out
    int local = b - a.e_k64a;
    int z = local/938, bx = local%938;
    int r0 = bx*64;
    f32x4 acc[4];
    #pragma unroll
    for (int cb = 0; cb < 4; ++cb) acc[cb] = (f32x4){0.f,0.f,0.f,0.f};
    gemm_mfma(a.rA[z], 64, ER, r0, a.rWh[z], a.rWl[z], 0, 2, acc);
    unsigned short* C = a.rC[z];
    int l = t & 63, w = t >> 6;
    int lr = l & 15, g = l >> 4;
    #pragma unroll
    for (int cb = 0; cb < 4; ++cb)
      #pragma unroll
      for (int i = 0; i < 4; ++i) {
        int r = r0 + w*16 + g*4 + i;
        if (r < ER) C[(size_t)r*64 + cb*16 + lr] = f2bf(acc[cb][i]);
      }
    return;
  }
  if (b < a.e_fe1c) {
    int gid = (b - a.e_k64r)*256 + t;
    if (gid < N_CNT*16) {
      int n = gid >> 4, q = (gid & 15) << 2;
      size_t o = (size_t)n*64 + q;
      float4 v = ld4(&a.f1[o]);
      float4 c = (n < U_CNT) ? ld4(&a.cui[o]) : ld4(&a.ciu[(size_t)(n-U_CNT)*64 + q]);
      st4(&a.fe1c[o], mul4(v, c));
    }
    return;
  }
  {
    int gid = (b - a.e_fe1c)*256 + t;
    if (gid < 6*320) {
      int k = gid/320, j = gid%320;
      a.sigt[gid] = 1.f/(1.f + __expf(-a.emb[k][j]));
    }
  }
}

// ========== MEGA2: fe5 gathers (bf16 re) | aspect gather_blend | reduce_blend (bf16 parts) ==========
#define FE5Z 10
struct Mega2Args {
  int split;
  const int* f_head[FE5Z]; const int2* f_node[FE5Z];
  const unsigned short* f_re[FE5Z]; const float* f_w[FE5Z]; const float* f_cui[FE5Z];
  const float* f_cmul[FE5Z]; float* f_outA[FE5Z]; float* f_outB[FE5Z]; int f_n[FE5Z];
  const int* gb_head[2]; const int2* gb_node[2];
  const float* gb_msg[2]; const float* gb_mask[2]; const float* gb_ca[2];
  const float* gb_fe[2]; const float* gb_cui[2]; float* gb_out[2]; int gb_n[2];
  const unsigned short* part[2]; int M[2];
  const float* bias[2]; const float* mask[2];
  const float* ca[2]; const float* fe[2]; const float* cui[2]; float* outb[2];
};

__global__ __launch_bounds__(256) void mega2(Mega2Args a)
{
  int b = blockIdx.x, t = threadIdx.x;
  int q = (t & 15) << 2;
  const int B_FE5 = 5*1250 + 5*938;                    // 10940
  if (b < B_FE5) {
    int z, bx;
    if (b < 6250) { z = 2*(b/1250) + 1; bx = b%1250; } // iu-lists (users)
    else { int l2 = b - 6250; z = 2*(l2/938); bx = l2%938; } // ui-lists (items)
    int d = bx*16 + (t >> 4);
    if (d >= a.f_n[z]) return;
    const int2* __restrict__ node = a.f_node[z];
    const unsigned short* __restrict__ re = a.f_re[z];
    const float* __restrict__ w = a.f_w[z];
    const float* __restrict__ cuiS = a.f_cui[z];
    float4 a0 = make_float4(0,0,0,0), a1 = a0;
    for (int cur = a.f_head[z][d]; cur >= 0; ) {
      int2 nd = node[cur];
      int e = cur;
      cur = nd.x;
      int s = nd.y;
      ushort4 r4 = *reinterpret_cast<const ushort4*>(&re[(size_t)e*64 + q]);
      float4 rv = make_float4(bf2f(r4.x), bf2f(r4.y), bf2f(r4.z), bf2f(r4.w));
      float4 cv = ld4(&cuiS[(size_t)s*64 + q]);
      float4 wv = ld4(&w[(size_t)s*64 + q]);
      a0 = add4(a0, mul4(add4(wv, rv), cv));
      a1 = add4(a1, mul4(rv, cv));
    }
    float4 c = ld4(&a.f_cmul[z][(size_t)d*64 + q]);
    size_t o = (size_t)d*320 + q;
    st4(&a.f_outA[z][o], mul4(a0, c));
    st4(&a.f_outB[z][o], mul4(a1, c));
    return;
  }
  int local = b - B_FE5;
  if (local < 2188) {                                   // gather_blend: u 1250 | i 938
    int side = (local >= 1250);
    int bx = side ? (local - 1250) : local;
    int d = bx*16 + (t >> 4);
    if (d >= a.gb_n[side]) return;
    const int2* __restrict__ node = a.gb_node[side];
    const float* __restrict__ msg = a.gb_msg[side];
    float4 acc = make_float4(0,0,0,0);
    for (int cur = a.gb_head[side][d]; cur >= 0; ) {
      int2 nd = node[cur];
      cur = nd.x;
      acc = add4(acc, ld4(&msg[(size_t)nd.y*64 + q]));
    }
    size_t o = (size_t)d*64 + q;
    float m = a.gb_mask[side][d], im = 1.f - m;
    float4 cav = ld4(&a.gb_ca[side][o]), fev = ld4(&a.gb_fe[side][o]), cv = ld4(&a.gb_cui[side][o]);
    st4(&a.gb_out[side][o], make_float4((m*(acc.x*cav.x) + im*fev.x)*cv.x,
                                        (m*(acc.y*cav.y) + im*fev.y)*cv.y,
                                        (m*(acc.z*cav.z) + im*fev.z)*cv.z,
                                        (m*(acc.w*cav.w) + im*fev.w)*cv.w));
    return;
  }
  local -= 2188;                                        // reduce_blend: u 1250 | i 938
  int side = (local >= 1250);
  int gid = (side ? (local - 1250) : local)*256 + t;
  int M = a.M[side];
  if (gid >= M*16) return;
  int n = gid >> 4;
  float4 acc = ld4(&a.bias[side][q]);
  const unsigned short* part = a.part[side];
  for (int s = 0; s < a.split; ++s) {
    ushort4 p4 = *reinterpret_cast<const ushort4*>(&part[((size_t)s*M + n)*64 + q]);
    acc = add4(acc, make_float4(bf2f(p4.x), bf2f(p4.y), bf2f(p4.z), bf2f(p4.w)));
  }
  size_t o = (size_t)n*64 + q;
  float m = a.mask[side][n], im = 1.f - m;
  float4 cav = ld4(&a.ca[side][o]), fev = ld4(&a.fe[side][o]), cv = ld4(&a.cui[side][o]);
  st4(&a.outb[side][o], make_float4((m*(acc.x*cav.x) + im*fev.x)*cv.x,
                                    (m*(acc.y*cav.y) + im*fev.y)*cv.y,
                                    (m*(acc.z*cav.z) + im*fev.z)*cv.z,
                                    (m*(acc.w*cav.w) + im*fev.w)*cv.w));
}

// ========== MEGA3: fused 3-acc gathers -> outputs 1..3 ==========
struct Mega3Args {
  int e_g3i;
  const int* head[2]; const int2* node[2];
  const float* msgA[2]; const float* msgB[2]; const float* msgC[2];
  const float* sigA[2]; const float* sigB[2]; const float* sigC[2];
  const float* cmul[2]; float* outA[2]; float* outB[2]; float* outC[2]; int n[2];
};

__global__ __launch_bounds__(256) void mega3(Mega3Args a)
{
  int b = blockIdx.x, t = threadIdx.x;
  int side = (b >= a.e_g3i);
  int bx = side ? (b - a.e_g3i) : b;
  int d = bx*16 + (t >> 4);
  if (d >= a.n[side]) return;
  int q = (t & 15) << 2;
  const int2* __restrict__ node = a.node[side];
  const float* __restrict__ msgA = a.msgA[side];
  const float* __restrict__ msgB = a.msgB[side];
  const float* __restrict__ msgC = a.msgC[side];
  const float* __restrict__ sigA = a.sigA[side];
  const float* __restrict__ sigB = a.sigB[side];
  const float* __restrict__ sigC = a.sigC[side];
  float4 a0 = make_float4(0,0,0,0), a1 = a0, a2 = a0;
  for (int cur = a.head[side][d]; cur >= 0; ) {
    int2 nd = node[cur];
    cur = nd.x;
    int s = nd.y & 0xFFFFF;
    int r = nd.y >> 20;
    size_t so = (size_t)s*64 + q;
    int ro = r*64 + q;
    a0 = add4(a0, mul4(ld4(&msgA[so]), ld4(&sigA[ro])));
    a1 = add4(a1, mul4(ld4(&msgB[so]), ld4(&sigB[ro])));
    a2 = add4(a2, mul4(ld4(&msgC[so]), ld4(&sigC[ro])));
  }
  size_t o = (size_t)d*64 + q;
  float4 c = ld4(&a.cmul[side][o]);
  st4(&a.outA[side][o], mul4(a0, c));
  st4(&a.outB[side][o], mul4(a1, c));
  st4(&a.outC[side][o], mul4(a2, c));
}

extern "C" void kernel_launch(void* const* d_in, const int* in_sizes, int n_in,
                              void* d_out, int out_size, void* d_ws, size_t ws_size,
                              hipStream_t stream)
{
  (void)in_sizes; (void)n_in; (void)out_size;
  auto F = [&](int i){ return (const float*)d_in[i]; };
  auto Ix = [&](int i){ return (const int*)d_in[i]; };

  const float* feature1 = F(0);
  const float* feature2 = F(1);
  const float* feature3 = F(2);
  const float* weightK[5]   = {F(3),F(4),F(5),F(6),F(7)};
  const float* W_review1 = F(8);
  const float* W_review2 = F(9);
  const float* rating_emb[6] = {F(10),F(11),F(12),F(13),F(14),F(15)};
  const float* W_aspect  = F(16);
  const float* W_aspect2 = F(17);
  const float* W_count_user = F(18);
  const float* b_count_user = F(19);
  const float* W_count_item = F(20);
  const float* b_count_item = F(21);
  const float* aspect_fe  = F(22);
  const float* aspect_cau = F(23);
  const float* aspect_cai = F(24);
  const float* user_cau = F(25);
  const float* user_cui = F(26);
  const float* item_cai = F(27);
  const float* item_ciu = F(28);
  const float* user_cuiK[5] = {F(29),F(31),F(33),F(35),F(37)};
  const float* item_ciuK[5] = {F(30),F(32),F(34),F(36),F(38)};
  const float* user_mask = F(39);
  const float* item_mask = F(40);
  const float* user_aspect_count = F(41);
  const float* item_aspect_count = F(42);
  const float* uiK_review[5] = {F(45),F(47),F(49),F(51),F(53)};
  const float* iuK_review[5] = {F(46),F(48),F(50),F(52),F(54)};
  const int* au_src = Ix(55); const int* au_dst = Ix(56);
  const int* ai_src = Ix(57); const int* ai_dst = Ix(58);
  const int* ui_src = Ix(59); const int* ui_dst = Ix(60); const int* ui_rating = Ix(61);
  const int* iu_src = Ix(62); const int* iu_dst = Ix(63); const int* iu_rating = Ix(64);
  const int* uiK_src[5] = {Ix(65),Ix(69),Ix(73),Ix(77),Ix(81)};
  const int* uiK_dst[5] = {Ix(66),Ix(70),Ix(74),Ix(78),Ix(82)};
  const int* iuK_src[5] = {Ix(67),Ix(71),Ix(75),Ix(79),Ix(83)};
  const int* iuK_dst[5] = {Ix(68),Ix(72),Ix(76),Ix(80),Ix(84)};

  float* out  = (float*)d_out;
  float* out2 = out + (size_t)N_CNT*64;
  float* out3 = out + 2*(size_t)N_CNT*64;
  float* out4 = out + 3*(size_t)N_CNT*64;              // (N,320)
  float* out5 = out + 8*(size_t)N_CNT*64;              // (N,320)

  // ---- workspace ----
  float* ws = (float*)d_ws;
  size_t off = 0;
  auto alloc = [&](size_t n){ float* p = ws + off; off += (n + 3) & ~(size_t)3; return p; };
  float* sigt   = alloc(6*320);
  float* msg_au = alloc((size_t)A_CNT*64);
  float* msg_ai = alloc((size_t)A_CNT*64);
  float* h_u_a  = alloc((size_t)U_CNT*64);
  float* h_i_a  = alloc((size_t)I_CNT*64);
  float* g_u    = alloc((size_t)U_CNT*64);
  float* g_i    = alloc((size_t)I_CNT*64);
  float* fe1c   = alloc((size_t)N_CNT*64);

  // W bf16 hi/lo fragment-order planes
  const size_t WP_USH = 2*131072 + 4*4096;             // 278528
  float* wpf = alloc(WP_USH);
  unsigned short* wph = (unsigned short*)wpf;
  unsigned short* wpl = wph + WP_USH;
  const size_t o_cu = 0, o_ci = 131072, o_a1 = 262144, o_a2 = 266240, o_r1 = 270336, o_r2 = 274432;

  // reb: 10 x ER x 64 bf16 (ushort)
  const size_t reUSH = (size_t)ER*64;
  float* rebf = alloc(10*reUSH/2);
  unsigned short* rebb[10];
  for (int j = 0; j < 10; ++j) rebb[j] = (unsigned short*)rebf + (size_t)j*reUSH;

  const int* l_src[NLIST] = {au_src, ai_src, ui_src, iu_src,
                             uiK_src[0],uiK_src[1],uiK_src[2],uiK_src[3],uiK_src[4],
                             iuK_src[0],iuK_src[1],iuK_src[2],iuK_src[3],iuK_src[4]};
  const int* l_dst[NLIST] = {au_dst, ai_dst, ui_dst, iu_dst,
                             uiK_dst[0],uiK_dst[1],uiK_dst[2],uiK_dst[3],uiK_dst[4],
                             iuK_dst[0],iuK_dst[1],iuK_dst[2],iuK_dst[3],iuK_dst[4]};
  int l_E[NLIST]    = {EAU,EAU,EUI,EUI, ER,ER,ER,ER,ER, ER,ER,ER,ER,ER};
  int l_nseg[NLIST] = {U_CNT,I_CNT,I_CNT,U_CNT, I_CNT,I_CNT,I_CNT,I_CNT,I_CNT,
                       U_CNT,U_CNT,U_CNT,U_CNT,U_CNT};

  int* ibase = (int*)(ws + off);
  int* lhead[NLIST]; int2* lnode[NLIST];
  size_t io = 0;
  for (int l = 0; l < NLIST; ++l) { lhead[l] = ibase + io; io += l_nseg[l]; }
  size_t head_ints = io;                                 // 245000
  for (int l = 0; l < NLIST; ++l) { lnode[l] = (int2*)(ibase + io); io += 2*(size_t)l_E[l]; }
  off += (io + 3) & ~(size_t)3;

  // parts: bf16 (ushort), SPLIT*N_CNT*64 ushorts
  int SPLIT = 4;
  while (SPLIT > 1 && (off + ((size_t)SPLIT*N_CNT*64 + 1)/2) * 4 > ws_size) SPLIT >>= 1;
  unsigned short* part_u = (unsigned short*)(ws + off);
  unsigned short* part_i = part_u + (size_t)SPLIT*U_CNT*64;

  // ---- PREP ----
  PrepArgs ap;
  ap.e_fill = (int)((head_ints/4 + 255)/256);           // 240
  ap.fillp = (int4*)ibase; ap.fill_n4 = (int)(head_ints/4);
  const float* wsrcs[6] = {W_count_user, W_count_item, W_aspect, W_aspect2, W_review1, W_review2};
  const size_t woffs[6] = {o_cu, o_ci, o_a1, o_a2, o_r1, o_r2};
  const int welems[6] = {131072, 131072, 4096, 4096, 4096, 4096};
  int prep_blocks = ap.e_fill;
  for (int z = 0; z < 6; ++z) {
    ap.wsrc[z] = wsrcs[z];
    ap.whi[z] = wph + woffs[z];
    ap.wlo[z] = wpl + woffs[z];
    ap.welems[z] = welems[z];
    ap.wblocks[z] = (welems[z] + 255)/256;
    prep_blocks += ap.wblocks[z];
  }
  prep<<<prep_blocks, 256, 0, stream>>>(ap);

  // ---- MEGA1 ----
  Mega1Args a1;
  const int B_SP    = SPLIT*313 + SPLIT*235;
  const int B_BUILD = 4*1172 + 10*235;                  // 7038
  const int B_K64A  = 64;
  const int B_K64R  = 10*938;                           // 9380
  const int B_FE1C  = (N_CNT*16 + 255)/256;             // 2188
  const int B_SIG   = 8;
  a1.e_sp    = B_SP;
  a1.e_build = B_SP + B_BUILD;
  a1.e_k64a  = a1.e_build + B_K64A;
  a1.e_k64r  = a1.e_k64a + B_K64R;
  a1.e_fe1c  = a1.e_k64r + B_FE1C;
  a1.split   = SPLIT;
  for (int k = 0; k < 6; ++k) a1.emb[k] = rating_emb[k];
  a1.sigt = sigt;
  a1.f1 = feature1; a1.cui = user_cui; a1.ciu = item_ciu; a1.fe1c = fe1c;
  a1.spA[0] = user_aspect_count; a1.spWh[0] = wph + o_cu; a1.spWl[0] = wpl + o_cu;
  a1.spPart[0] = part_u; a1.spM[0] = U_CNT;
  a1.spA[1] = item_aspect_count; a1.spWh[1] = wph + o_ci; a1.spWl[1] = wpl + o_ci;
  a1.spPart[1] = part_i; a1.spM[1] = I_CNT;
  a1.aA[0]=aspect_fe; a1.aWh[0]=wph+o_a1; a1.aWl[0]=wpl+o_a1; a1.aMul[0]=aspect_cau; a1.aC[0]=msg_au;
  a1.aA[1]=aspect_fe; a1.aWh[1]=wph+o_a2; a1.aWl[1]=wpl+o_a2; a1.aMul[1]=aspect_cai; a1.aC[1]=msg_ai;
  for (int k = 0; k < 5; ++k) {
    a1.rA[k]   = uiK_review[k]; a1.rWh[k]   = wph+o_r1; a1.rWl[k]   = wpl+o_r1; a1.rC[k]   = rebb[k];
    a1.rA[5+k] = iuK_review[k]; a1.rWh[5+k] = wph+o_r2; a1.rWl[5+k] = wpl+o_r2; a1.rC[5+k] = rebb[5+k];
  }
  for (int l = 0; l < NLIST; ++l) {
    a1.bsrc[l]=l_src[l]; a1.bdst[l]=l_dst[l];
    a1.node[l]=lnode[l]; a1.head[l]=lhead[l];
  }
  a1.rat2 = ui_rating; a1.rat3 = iu_rating;
  mega1<<<a1.e_fe1c + B_SIG, 256, 0, stream>>>(a1);

  // ---- MEGA2 ----
  Mega2Args a2;
  a2.split = SPLIT;
  for (int k = 0; k < 5; ++k) {
    int z = 2*k;                                        // ui-side (dst=items)
    a2.f_head[z]=lhead[4+k]; a2.f_node[z]=lnode[4+k];
    a2.f_re[z]=rebb[k]; a2.f_w[z]=weightK[k]; a2.f_cui[z]=user_cuiK[k]; a2.f_cmul[z]=item_ciuK[k];
    a2.f_outA[z]=out4 + (size_t)U_CNT*320 + (size_t)k*64;
    a2.f_outB[z]=out5 + (size_t)U_CNT*320 + (size_t)k*64;
    a2.f_n[z]=I_CNT;
    a2.f_head[z+1]=lhead[9+k]; a2.f_node[z+1]=lnode[9+k]; // iu-side (dst=users)
    a2.f_re[z+1]=rebb[5+k]; a2.f_w[z+1]=weightK[k] + (size_t)U_CNT*64;
    a2.f_cui[z+1]=item_ciuK[k]; a2.f_cmul[z+1]=user_cuiK[k];
    a2.f_outA[z+1]=out4 + (size_t)k*64;
    a2.f_outB[z+1]=out5 + (size_t)k*64;
    a2.f_n[z+1]=U_CNT;
  }
  a2.gb_head[0]=lhead[0]; a2.gb_node[0]=lnode[0]; a2.gb_msg[0]=msg_au;
  a2.gb_mask[0]=user_mask; a2.gb_ca[0]=user_cau; a2.gb_fe[0]=feature2;
  a2.gb_cui[0]=user_cui; a2.gb_out[0]=h_u_a; a2.gb_n[0]=U_CNT;
  a2.gb_head[1]=lhead[1]; a2.gb_node[1]=lnode[1]; a2.gb_msg[1]=msg_ai;
  a2.gb_mask[1]=item_mask; a2.gb_ca[1]=item_cai; a2.gb_fe[1]=feature2 + (size_t)U_CNT*64;
  a2.gb_cui[1]=item_ciu; a2.gb_out[1]=h_i_a; a2.gb_n[1]=I_CNT;
  a2.part[0]=part_u; a2.M[0]=U_CNT; a2.bias[0]=b_count_user; a2.mask[0]=user_mask;
  a2.ca[0]=user_cau; a2.fe[0]=feature3; a2.cui[0]=user_cui; a2.outb[0]=g_u;
  a2.part[1]=part_i; a2.M[1]=I_CNT; a2.bias[1]=b_count_item; a2.mask[1]=item_mask;
  a2.ca[1]=item_cai; a2.fe[1]=feature3 + (size_t)U_CNT*64; a2.cui[1]=item_ciu; a2.outb[1]=g_i;
  const int B_M2 = (5*1250 + 5*938) + 2188 + 2188;
  mega2<<<B_M2, 256, 0, stream>>>(a2);

  // ---- MEGA3 ----
  Mega3Args a3;
  a3.e_g3i = 938;
  a3.head[0]=lhead[2]; a3.node[0]=lnode[2];
  a3.msgA[0]=h_u_a; a3.msgB[0]=g_u; a3.msgC[0]=fe1c;
  a3.sigA[0]=sigt + 0*320; a3.sigB[0]=sigt + 2*320; a3.sigC[0]=sigt + 4*320;
  a3.cmul[0]=item_ciu;
  a3.outA[0]=out + (size_t)U_CNT*64; a3.outB[0]=out2 + (size_t)U_CNT*64; a3.outC[0]=out3 + (size_t)U_CNT*64;
  a3.n[0]=I_CNT;
  a3.head[1]=lhead[3]; a3.node[1]=lnode[3];
  a3.msgA[1]=h_i_a; a3.msgB[1]=g_i; a3.msgC[1]=fe1c + (size_t)U_CNT*64;
  a3.sigA[1]=sigt + 1*320; a3.sigB[1]=sigt + 3*320; a3.sigC[1]=sigt + 5*320;
  a3.cmul[1]=user_cui;
  a3.outA[1]=out; a3.outB[1]=out2; a3.outC[1]=out3;
  a3.n[1]=U_CNT;
  mega3<<<938 + 1250, 256, 0, stream>>>(a3);
}